// Round 8
// baseline (292.035 us; speedup 1.0000x reference)
//
#include <hip/hip_runtime.h>

#define B_   256
#define E_   64
#define G_   2000
#define P_   512
#define K2   2016      // G padded to multiple of BK (xbt zero-filled)
#define NOCT (K2/8)    // 252 k-octets
#define BK   32
#define NS   (K2/BK)   // 63 K-steps
#define PT   16        // p columns per block (one 16-wide MFMA tile)

typedef __bf16 bf16x8 __attribute__((ext_vector_type(8)));
typedef float floatx4 __attribute__((ext_vector_type(4)));

// xbt[oct][row][8] bf16: A-frag for (oct,16 rows) = 256B contiguous.
__global__ __launch_bounds__(256)
void cvt_xt_kernel(const float* __restrict__ x, __bf16* __restrict__ xbt) {
    const int r   = threadIdx.x;     // row 0..255
    const int oct = blockIdx.x;      // 0..251
    bf16x8 v;
    #pragma unroll
    for (int j = 0; j < 8; ++j) {
        const int k = oct * 8 + j;
        v[j] = (k < G_) ? (__bf16)x[(size_t)r * G_ + k] : (__bf16)0.f;
    }
    *(bf16x8*)&xbt[((size_t)oct * 256 + r) * 8] = v;   // 4KB contiguous per block
}

// Barrier-free streaming GEMM. Block = (e, 16-col p-slab); wave wv owns
// rows wv*64..wv*64+63 — disjoint outputs, zero inter-wave communication.
// Per 32-k step per wave: 8 W + 8 M strided dwords (lane: p=ln, g=hi*8+j ->
// 4 x 64B fully-used lines/instr), 4 A b128 from xbt (4 x 256B contiguous),
// 4 MFMA 16x16x32. W/M prefetched one step ahead in named register sets.
template<bool USE_WS>
__global__ __launch_bounds__(256, 4)
void masked_gemm_kernel(const float* __restrict__ x,
                        const __bf16* __restrict__ xbt,
                        const float* __restrict__ weight,
                        const float* __restrict__ bias,
                        const float* __restrict__ mask,
                        float* __restrict__ out)
{
    const int tid  = threadIdx.x;
    const int lane = tid & 63;
    const int wv   = tid >> 6;
    const int ln   = lane & 15;          // p col / A row-in-tile
    const int hi   = lane >> 4;          // k-octet group 0..3

    const int bid = blockIdx.x;          // 2048 blocks
    const int xcd = bid & 7;
    const int jj  = bid >> 3;            // 0..255
    const int pt  = xcd * 4 + (jj & 3);  // p-tile 0..31 (4 per XCD: mask L2-hot)
    const int e   = jj >> 2;             // 0..63
    const int p0  = pt * PT;
    const int mrow0 = wv * 64;

    const float* wcol = weight + (size_t)e * G_ * P_ + p0 + ln;
    const float* mcol = mask + p0 + ln;

    floatx4 acc[4];
    #pragma unroll
    for (int i = 0; i < 4; ++i) acc[i] = (floatx4)0.f;

    float wA[8], mA[8], wB[8], mB[8];

#define GATHER(S, W, M)                                                  \
    { _Pragma("unroll")                                                  \
      for (int q = 0; q < 8; ++q) {                                      \
          int g = (S) * BK + hi * 8 + q;                                 \
          if (g > G_ - 1) g = G_ - 1;  /* clamp: A k-tail is exact 0 */  \
          W[q] = wcol[(size_t)g * P_];                                   \
          M[q] = mcol[(size_t)g * P_];                                   \
      } }

#define STEP(S, W, M)                                                    \
    { bf16x8 bfrag;                                                      \
      _Pragma("unroll")                                                  \
      for (int q = 0; q < 8; ++q) bfrag[q] = (__bf16)(W[q] * M[q]);      \
      _Pragma("unroll")                                                  \
      for (int mi = 0; mi < 4; ++mi) {                                   \
          bf16x8 a;                                                      \
          if (USE_WS) {                                                  \
              a = *(const bf16x8*)&xbt[((size_t)((S) * 4 + hi) * 256 +   \
                                        mrow0 + mi * 16 + ln) * 8];      \
          } else {                                                       \
              const int row = mrow0 + mi * 16 + ln;                      \
              _Pragma("unroll")                                          \
              for (int q = 0; q < 8; ++q) {                              \
                  const int k = (S) * BK + hi * 8 + q;                   \
                  a[q] = (k < G_) ? (__bf16)x[(size_t)row * G_ + k]      \
                                  : (__bf16)0.f;                         \
              }                                                          \
          }                                                              \
          acc[mi] = __builtin_amdgcn_mfma_f32_16x16x32_bf16(             \
                        a, bfrag, acc[mi], 0, 0, 0);                     \
      } }

    // rolling depth-1 prefetch; no barriers anywhere
    GATHER(0, wA, mA);
    #pragma unroll 1
    for (int it = 0; it < (NS - 1) / 2; ++it) {          // 31 iters: steps 0..61
        const int s = 2 * it;
        GATHER(s + 1, wB, mB);
        STEP(s, wA, mA);
        GATHER(s + 2, wA, mA);
        STEP(s + 1, wB, mB);
    }
    STEP(NS - 1, wA, mA);                                // step 62

#undef GATHER
#undef STEP

    // epilogue: D col n=p=ln, row m = mi*16 + hi*4 + q
    const float bv = bias[e * P_ + p0 + ln];
    #pragma unroll
    for (int mi = 0; mi < 4; ++mi) {
        #pragma unroll
        for (int q = 0; q < 4; ++q) {
            const int b = mrow0 + mi * 16 + hi * 4 + q;
            __builtin_nontemporal_store(acc[mi][q] + bv,
                &out[(size_t)b * (E_ * P_) + (size_t)e * P_ + p0 + ln]);
        }
    }
}

extern "C" void kernel_launch(void* const* d_in, const int* in_sizes, int n_in,
                              void* d_out, int out_size, void* d_ws, size_t ws_size,
                              hipStream_t stream) {
    const float* x      = (const float*)d_in[0];
    const float* weight = (const float*)d_in[1];
    const float* bias   = (const float*)d_in[2];
    const float* mask   = (const float*)d_in[3];
    float* out = (float*)d_out;

    const size_t xbt_bytes = (size_t)NOCT * 256 * 8 * sizeof(__bf16);
    if (ws_size >= xbt_bytes) {
        __bf16* xbt = (__bf16*)d_ws;
        cvt_xt_kernel<<<dim3(NOCT), dim3(256), 0, stream>>>(x, xbt);
        masked_gemm_kernel<true><<<dim3(2048), dim3(256), 0, stream>>>(x, xbt, weight, bias, mask, out);
    } else {
        masked_gemm_kernel<false><<<dim3(2048), dim3(256), 0, stream>>>(x, nullptr, weight, bias, mask, out);
    }
}

// Round 9
// 183.612 us; speedup vs baseline: 1.5905x; 1.5905x over previous
//
#include <hip/hip_runtime.h>

#define B_   256
#define E_   64
#define G_   2000
#define P_   512
#define BK   32
#define NS   63          // K2 = 2016, zero-padded in xbt / mask bits
#define NOCT (NS*4)      // 252 k-octets
#define PT   32          // p columns per block

typedef __bf16 bf16x8 __attribute__((ext_vector_type(8)));
typedef float floatx16 __attribute__((ext_vector_type(16)));

// xbt[oct][row][8] bf16: the A-fragment for (k-octet, row) is 16B contiguous.
__global__ __launch_bounds__(256)
void cvt_xt_kernel(const float* __restrict__ x, __bf16* __restrict__ xbt) {
    const int r   = threadIdx.x;     // row 0..255
    const int oct = blockIdx.x;      // 0..251
    bf16x8 v;
    #pragma unroll
    for (int j = 0; j < 8; ++j) {
        const int k = oct * 8 + j;
        v[j] = (k < G_) ? (__bf16)x[(size_t)r * G_ + k] : (__bf16)0.f;
    }
    *(bf16x8*)&xbt[((size_t)oct * 256 + r) * 8] = v;
}

// mb[gd][p]: bit j of mb[gd*512+p] = (mask[gd*32+j][p] != 0); g>=2000 -> 0.
__global__ __launch_bounds__(512)
void mask_bits_kernel(const float* __restrict__ mask, unsigned* __restrict__ mb) {
    const int p  = threadIdx.x;      // 0..511
    const int gd = blockIdx.x;       // 0..62
    unsigned v = 0;
    #pragma unroll
    for (int j = 0; j < 32; ++j) {
        const int g = gd * 32 + j;
        if (g < G_) v |= (mask[(size_t)g * P_ + p] != 0.f ? 1u : 0u) << j;
    }
    mb[(size_t)gd * P_ + p] = v;
}

// Barrier-free, LDS-free streaming GEMM. Block = (e, 32-col p-slab), 8 waves
// x 32 rows. Per wave per 32-k step: 16 strided W dwords (4 fully-used 64B
// lines / instr), 1 mask-bit dword (L1-hot), 2 A b128 (L2), 2 MFMA 32x32x16.
// W prefetched depth-2 (3 named reg sets), A depth-1 (2 sets); issue order
// per step is pinned with sched_barrier(0): [A(s+1)] [W(s+2)] [consume(s)],
// so waiting on A(s)/W(s) leaves W(s+1)+W(s+2) (~8KB/wave) in flight.
template<bool USE_WS>
__global__ __launch_bounds__(512, 4)
void masked_gemm_kernel(const float* __restrict__ x,
                        const __bf16* __restrict__ xbt,
                        const unsigned* __restrict__ mbits,
                        const float* __restrict__ weight,
                        const float* __restrict__ bias,
                        const float* __restrict__ mask,
                        float* __restrict__ out)
{
    const int tid  = threadIdx.x;
    const int lane = tid & 63;
    const int wv   = tid >> 6;           // wave 0..7: rows wv*32..wv*32+31
    const int ln   = lane & 31;          // p col / A row in tile
    const int hi   = lane >> 5;          // k-octet half

    const int bid = blockIdx.x;          // 1024 blocks
    const int e   = bid >> 4;            // 0..63
    const int p0  = (bid & 15) * PT;
    const int mrow = wv * 32 + ln;       // global A row 0..255

    // per-lane bases (hi folded in once)
    const float*    wcol  = weight + (size_t)e * G_ * P_ + (size_t)(hi * 8) * P_ + p0 + ln;
    const float*    wraw  = weight + (size_t)e * G_ * P_ + p0 + ln;   // tail clamp path
    const unsigned* mbp   = USE_WS ? (mbits + p0 + ln) : nullptr;
    const __bf16*   xbase = USE_WS ? (xbt + ((size_t)hi * 256 + mrow) * 8) : nullptr;

    floatx16 acc = (floatx16)0.f;

    float w0[16], w1[16], w2[16];
    unsigned b0 = 0, b1 = 0, b2 = 0;
    bf16x8 a0[2], a1[2];

#define A_LOAD(S, AS_)                                                    \
    { if (USE_WS) {                                                       \
        (AS_)[0] = *(const bf16x8*)(xbase + (size_t)((S) * 4 + 0) * 2048);\
        (AS_)[1] = *(const bf16x8*)(xbase + (size_t)((S) * 4 + 2) * 2048);\
      } else {                                                            \
        _Pragma("unroll")                                                 \
        for (int kh = 0; kh < 2; ++kh)                                    \
          _Pragma("unroll")                                               \
          for (int j = 0; j < 8; ++j) {                                   \
            const int k = (S) * 32 + kh * 16 + hi * 8 + j;                \
            (AS_)[kh][j] = (k < G_) ? (__bf16)x[(size_t)mrow * G_ + k]    \
                                    : (__bf16)0.f;                        \
          }                                                               \
      } }

#define W_GATHER(S, WS_, MB_)                                             \
    { _Pragma("unroll")                                                   \
      for (int kh = 0; kh < 2; ++kh)                                      \
        _Pragma("unroll")                                                 \
        for (int j = 0; j < 8; ++j)                                       \
            (WS_)[kh * 8 + j] = wcol[(size_t)((S) * 32 + kh * 16 + j) * P_]; \
      if (USE_WS) (MB_) = mbp[(size_t)(S) * P_]; }

#define W_GATHER_T(S, WS_, MB_)                                           \
    { _Pragma("unroll")                                                   \
      for (int kh = 0; kh < 2; ++kh)                                      \
        _Pragma("unroll")                                                 \
        for (int j = 0; j < 8; ++j) {                                     \
            int g = (S) * 32 + kh * 16 + hi * 8 + j;                      \
            if (g > G_ - 1) g = G_ - 1;   /* A k-tail == 0 covers it */   \
            (WS_)[kh * 8 + j] = wraw[(size_t)g * P_];                     \
        }                                                                 \
      if (USE_WS) (MB_) = mbp[(size_t)(S) * P_]; }

#define CONSUME(S, WS_, MB_, AS_)                                         \
    { _Pragma("unroll")                                                   \
      for (int kh = 0; kh < 2; ++kh) {                                    \
        bf16x8 bf;                                                        \
        if (USE_WS) {                                                     \
            const unsigned sh = (MB_) >> (kh * 16 + hi * 8);              \
            _Pragma("unroll")                                             \
            for (int j = 0; j < 8; ++j)                                   \
                bf[j] = ((sh >> j) & 1u) ? (__bf16)(WS_)[kh * 8 + j]      \
                                         : (__bf16)0.f;                   \
        } else {                                                          \
            _Pragma("unroll")                                             \
            for (int j = 0; j < 8; ++j) {                                 \
                int g = (S) * 32 + kh * 16 + hi * 8 + j;                  \
                if (g > G_ - 1) g = G_ - 1;                               \
                bf[j] = (__bf16)((WS_)[kh * 8 + j] *                      \
                                 mask[(size_t)g * P_ + p0 + ln]);         \
            }                                                             \
        }                                                                 \
        acc = __builtin_amdgcn_mfma_f32_32x32x16_bf16((AS_)[kh], bf, acc, 0, 0, 0); \
      } }

#define BODY(S, AN_, WF_, BF_, WC_, BC_, AC_)                             \
    { __builtin_amdgcn_sched_barrier(0);                                  \
      A_LOAD((S) + 1, AN_);                                               \
      __builtin_amdgcn_sched_barrier(0);                                  \
      W_GATHER((S) + 2, WF_, BF_);                                        \
      __builtin_amdgcn_sched_barrier(0);                                  \
      CONSUME((S), WC_, BC_, AC_); }

    // ---- prologue: FIFO = W(0), A(0), W(1) ----
    W_GATHER(0, w0, b0);
    A_LOAD(0, a0);
    W_GATHER(1, w1, b1);

    // ---- steady state: steps 0..59 (all prefetches in range) ----
    #pragma unroll 1
    for (int it = 0; it < 10; ++it) {
        const int sb = it * 6;
        BODY(sb + 0, a1, w2, b2, w0, b0, a0);
        BODY(sb + 1, a0, w0, b0, w1, b1, a1);
        BODY(sb + 2, a1, w1, b1, w2, b2, a0);
        BODY(sb + 3, a0, w2, b2, w0, b0, a1);
        BODY(sb + 4, a1, w0, b0, w1, b1, a0);
        BODY(sb + 5, a0, w1, b1, w2, b2, a1);
    }

    // ---- tail: steps 60, 61, 62 ----
    __builtin_amdgcn_sched_barrier(0);
    A_LOAD(61, a1);
    __builtin_amdgcn_sched_barrier(0);
    W_GATHER_T(62, w2, b2);
    __builtin_amdgcn_sched_barrier(0);
    CONSUME(60, w0, b0, a0);
    __builtin_amdgcn_sched_barrier(0);
    A_LOAD(62, a0);
    __builtin_amdgcn_sched_barrier(0);
    CONSUME(61, w1, b1, a1);
    __builtin_amdgcn_sched_barrier(0);
    CONSUME(62, w2, b2, a0);

#undef A_LOAD
#undef W_GATHER
#undef W_GATHER_T
#undef CONSUME
#undef BODY

    // ---- epilogue: D col = p0+ln, row m = (r&3)+8*(r>>2)+4*hi ----
    const int pcol = p0 + ln;
    const float bv = bias[e * P_ + pcol];
    #pragma unroll
    for (int r = 0; r < 16; ++r) {
        const int m = (r & 3) + 8 * (r >> 2) + 4 * hi;
        const int b = wv * 32 + m;
        __builtin_nontemporal_store(acc[r] + bv,
            &out[(size_t)b * (E_ * P_) + (size_t)e * P_ + pcol]);
    }
}

extern "C" void kernel_launch(void* const* d_in, const int* in_sizes, int n_in,
                              void* d_out, int out_size, void* d_ws, size_t ws_size,
                              hipStream_t stream) {
    const float* x      = (const float*)d_in[0];
    const float* weight = (const float*)d_in[1];
    const float* bias   = (const float*)d_in[2];
    const float* mask   = (const float*)d_in[3];
    float* out = (float*)d_out;

    const size_t mb_bytes  = (size_t)NS * P_ * sizeof(unsigned);   // 129 KB
    const size_t xbt_off   = 131072;
    const size_t xbt_bytes = (size_t)NOCT * 256 * 8 * sizeof(__bf16);  // ~1 MB

    if (ws_size >= xbt_off + xbt_bytes && mb_bytes <= xbt_off) {
        unsigned* mb  = (unsigned*)d_ws;
        __bf16*   xbt = (__bf16*)((char*)d_ws + xbt_off);
        mask_bits_kernel<<<dim3(NS), dim3(512), 0, stream>>>(mask, mb);
        cvt_xt_kernel<<<dim3(NOCT), dim3(256), 0, stream>>>(x, xbt);
        masked_gemm_kernel<true><<<dim3(1024), dim3(512), 0, stream>>>(
            x, xbt, mb, weight, bias, mask, out);
    } else {
        masked_gemm_kernel<false><<<dim3(1024), dim3(512), 0, stream>>>(
            x, nullptr, nullptr, weight, bias, mask, out);
    }
}